// Round 1
// baseline (14769.646 us; speedup 1.0000x reference)
//
#include <hip/hip_runtime.h>
#include <cstdint>
#include <cstddef>

// Problem constants
// G=256 graphs, NP=1000 points, K=8 neighbors, H=8 heads, DH=10, D=80, NL=10 layers

__device__ __forceinline__ void tile_dot20(const float* __restrict__ in, int rowStrideF,
                                           const float* __restrict__ wcol, float acc[8]) {
  // 8 rows x 80 k-elements
  #pragma unroll
  for (int j = 0; j < 8; ++j) {
    const float4* r4 = reinterpret_cast<const float4*>(in + j * rowStrideF);
    #pragma unroll
    for (int kq = 0; kq < 20; ++kq) {
      float4 hv = r4[kq];
      acc[j] = fmaf(hv.x, wcol[4 * kq + 0], acc[j]);
      acc[j] = fmaf(hv.y, wcol[4 * kq + 1], acc[j]);
      acc[j] = fmaf(hv.z, wcol[4 * kq + 2], acc[j]);
      acc[j] = fmaf(hv.w, wcol[4 * kq + 3], acc[j]);
    }
  }
}

template <int KQ>
__device__ __forceinline__ void tile_dotk(const float* __restrict__ in, int rowStrideF,
                                          const float* __restrict__ wcol, float acc[8]) {
  #pragma unroll
  for (int j = 0; j < 8; ++j) {
    const float4* r4 = reinterpret_cast<const float4*>(in + j * rowStrideF);
    #pragma unroll
    for (int kq = 0; kq < KQ; ++kq) {
      float4 hv = r4[kq];
      acc[j] = fmaf(hv.x, wcol[4 * kq + 0], acc[j]);
      acc[j] = fmaf(hv.y, wcol[4 * kq + 1], acc[j]);
      acc[j] = fmaf(hv.z, wcol[4 * kq + 2], acc[j]);
      acc[j] = fmaf(hv.w, wcol[4 * kq + 3], acc[j]);
    }
  }
}

// ---------------- KNN: exact reference-order arithmetic, stable tie-break ----------------
__global__ __launch_bounds__(256) void knn_kernel(const float* __restrict__ hf, int* __restrict__ nbr) {
  __shared__ float cs[3000];  // 1000 x 3 coords of this graph
  int b = blockIdx.x;
  int g = b >> 2;
  int q = b & 3;
  for (int i = threadIdx.x; i < 3000; i += 256) {
    cs[i] = hf[((size_t)g * 1000 + (i / 3)) * 9 + (i % 3)];
  }
  __syncthreads();
  int tid = threadIdx.x;
  if (tid < 250) {
    int n = q * 250 + tid;
    float cx = cs[n * 3 + 0], cy = cs[n * 3 + 1], cz = cs[n * 3 + 2];
    float bd[8];
    int bi[8];
    #pragma unroll
    for (int q2 = 0; q2 < 8; ++q2) { bd[q2] = 3.402823466e38f; bi[q2] = 0; }
    for (int j = 0; j < 1000; ++j) {
      // Match numpy bitwise: (xi-xj)^2 elementwise, sum order (d0+d1)+d2, no FMA contraction
      float dx = __fsub_rn(cx, cs[j * 3 + 0]);
      float dy = __fsub_rn(cy, cs[j * 3 + 1]);
      float dz = __fsub_rn(cz, cs[j * 3 + 2]);
      float d2 = __fadd_rn(__fadd_rn(__fmul_rn(dx, dx), __fmul_rn(dy, dy)), __fmul_rn(dz, dz));
      if (d2 < bd[7]) {
        bd[7] = d2; bi[7] = j;
        #pragma unroll
        for (int q2 = 7; q2 >= 1; --q2) {
          if (bd[q2] < bd[q2 - 1]) {  // strict: keeps lower index first on ties (top_k semantics)
            float tf = bd[q2]; bd[q2] = bd[q2 - 1]; bd[q2 - 1] = tf;
            int ti = bi[q2]; bi[q2] = bi[q2 - 1]; bi[q2 - 1] = ti;
          }
        }
      }
    }
    #pragma unroll
    for (int kk = 0; kk < 8; ++kk) nbr[((size_t)g * 1000 + n) * 8 + kk] = bi[kk];
  }
}

// ---------------- BatchNorm stats (deterministic two-stage) ----------------
__global__ __launch_bounds__(256) void bn_stat1(const float* __restrict__ hf, float* __restrict__ partial) {
  __shared__ float red[4][18];
  int row = blockIdx.x * 256 + threadIdx.x;  // exactly 256000 rows
  float s[9], ss[9];
  #pragma unroll
  for (int f = 0; f < 9; ++f) {
    float v = hf[(size_t)row * 9 + f];
    s[f] = v;
    ss[f] = v * v;
  }
  for (int off = 32; off > 0; off >>= 1) {
    #pragma unroll
    for (int f = 0; f < 9; ++f) {
      s[f] += __shfl_down(s[f], off);
      ss[f] += __shfl_down(ss[f], off);
    }
  }
  int wid = threadIdx.x >> 6, lane = threadIdx.x & 63;
  if (lane == 0) {
    #pragma unroll
    for (int f = 0; f < 9; ++f) { red[wid][f] = s[f]; red[wid][9 + f] = ss[f]; }
  }
  __syncthreads();
  if (threadIdx.x < 18) {
    partial[(size_t)blockIdx.x * 18 + threadIdx.x] =
        red[0][threadIdx.x] + red[1][threadIdx.x] + red[2][threadIdx.x] + red[3][threadIdx.x];
  }
}

__global__ __launch_bounds__(256) void bn_stat2(const float* __restrict__ partial, float* __restrict__ stats) {
  __shared__ double sd[9][28], qd[9][28];
  int tid = threadIdx.x;
  if (tid < 252) {
    int f = tid % 9, gq = tid / 9;
    double s = 0.0, q = 0.0;
    for (int b = gq; b < 1000; b += 28) {
      s += (double)partial[b * 18 + f];
      q += (double)partial[b * 18 + 9 + f];
    }
    sd[f][gq] = s;
    qd[f][gq] = q;
  }
  __syncthreads();
  if (tid < 9) {
    double s = 0.0, q = 0.0;
    for (int g2 = 0; g2 < 28; ++g2) { s += sd[tid][g2]; q += qd[tid][g2]; }
    double mu = s / 256000.0;
    double var = q / 256000.0 - mu * mu;
    stats[tid] = (float)mu;
    stats[9 + tid] = (float)(1.0 / sqrt(var + 1e-5));
  }
}

// ---------------- Embed: normalize + (9->80) ----------------
__global__ __launch_bounds__(320) void embed_kernel(const float* __restrict__ hf, const float* __restrict__ stats,
                                                    const float* __restrict__ gamma, const float* __restrict__ beta,
                                                    const float* __restrict__ We, const float* __restrict__ be,
                                                    float* __restrict__ h) {
  __shared__ __align__(16) float xs[40 * 9];
  size_t p0 = (size_t)blockIdx.x * 40;
  for (int i = threadIdx.x; i < 360; i += 320) {
    int f = i % 9;
    float x = hf[p0 * 9 + i];
    xs[i] = (x - stats[f]) * stats[9 + f] * gamma[f] + beta[f];
  }
  __syncthreads();
  int c = threadIdx.x % 80, pg = threadIdx.x / 80;  // pg in 0..3 -> 10 points each
  float we[9];
  #pragma unroll
  for (int f = 0; f < 9; ++f) we[f] = We[f * 80 + c];
  float bias = be[c];
  for (int pp = 0; pp < 10; ++pp) {
    int p = pg * 10 + pp;
    float acc = 0.f;
    #pragma unroll
    for (int f = 0; f < 9; ++f) acc = fmaf(xs[p * 9 + f], we[f], acc);
    h[(p0 + p) * 80 + c] = acc + bias;
  }
}

// ---------------- K,V projection (fused two 80x80 GEMMs) ----------------
__global__ __launch_bounds__(320) void kv_kernel(const float* __restrict__ h, const float* __restrict__ Wk,
                                                 const float* __restrict__ Wv, float* __restrict__ kb,
                                                 float* __restrict__ vb) {
  __shared__ __align__(16) float hs[40 * 80];
  size_t p0 = (size_t)blockIdx.x * 40;
  for (int i = threadIdx.x; i < 3200; i += 320) hs[i] = h[p0 * 80 + i];
  __syncthreads();
  int c2 = threadIdx.x % 160;
  int grp = threadIdx.x / 160;  // 0..1
  const float* W = (c2 < 80) ? Wk : Wv;
  float* out = (c2 < 80) ? kb : vb;
  int c = (c2 < 80) ? c2 : (c2 - 80);
  float wcol[80];
  #pragma unroll
  for (int kk = 0; kk < 80; ++kk) wcol[kk] = W[kk * 80 + c];
  #pragma unroll
  for (int tt = 0; tt < 3; ++tt) {
    int t = grp + 2 * tt;  // grp0:{0,2,4} grp1:{1,3}
    if (t < 5) {
      float acc[8] = {0, 0, 0, 0, 0, 0, 0, 0};
      tile_dot20(hs + t * 640, 80, wcol, acc);
      #pragma unroll
      for (int j = 0; j < 8; ++j) out[(p0 + t * 8 + j) * 80 + c] = acc[j];
    }
  }
}

// ---------------- Fused: q GEMM + neighbor attention + Wo GEMM + FFN (per 40-point tile) ----------------
__global__ __launch_bounds__(320) void battn_kernel(const float* __restrict__ h, const float* __restrict__ kb,
                                                    const float* __restrict__ vb, const int* __restrict__ nbr,
                                                    const float* __restrict__ Wq, const float* __restrict__ Wo,
                                                    const float* __restrict__ bo, const float* __restrict__ W1,
                                                    const float* __restrict__ b1, const float* __restrict__ W2,
                                                    const float* __restrict__ b2, float* __restrict__ hout) {
  __shared__ __align__(16) float hs[3200];   // h tile (residual + GEMM input)
  __shared__ __align__(16) float qa[3200];   // q, then attn
  __shared__ __align__(16) float h2[3200];   // h + attn@Wo + bo
  __shared__ __align__(16) float ts[6400];   // relu(h2@W1+b1)
  int b = blockIdx.x;
  // XCD-aware swizzle: graph's 25 blocks land on one XCD (graph k/v = 640KB << 4MB L2)
  int xcd = b & 7;
  int r = b >> 3;                  // 0..799
  int graph = (xcd << 5) + (r / 25);
  int jb = r % 25;
  size_t gbase = (size_t)graph * 1000;
  size_t pbase = gbase + (size_t)jb * 40;
  int tid = threadIdx.x;
  for (int i = tid; i < 3200; i += 320) hs[i] = h[pbase * 80 + i];
  __syncthreads();
  // ---- q = h @ Wq ----
  {
    int c = tid % 80, grp = tid / 80;  // 0..3
    float wcol[80];
    #pragma unroll
    for (int kk = 0; kk < 80; ++kk) wcol[kk] = Wq[kk * 80 + c];
    #pragma unroll
    for (int tt = 0; tt < 2; ++tt) {
      int t = grp + 4 * tt;  // grp0:{0,4} others 1 tile
      if (t < 5) {
        float acc[8] = {0, 0, 0, 0, 0, 0, 0, 0};
        tile_dot20(hs + t * 640, 80, wcol, acc);
        #pragma unroll
        for (int j = 0; j < 8; ++j) qa[(t * 8 + j) * 80 + c] = acc[j];
      }
    }
  }
  __syncthreads();
  // ---- attention: thread = (point, head) ----
  {
    int p = tid >> 3, hh = tid & 7;
    int n = jb * 40 + p;
    float qv[10];
    #pragma unroll
    for (int d = 0; d < 10; ++d) qv[d] = qa[p * 80 + hh * 10 + d];
    int nb[8];
    #pragma unroll
    for (int kk = 0; kk < 8; ++kk) nb[kk] = nbr[(gbase + n) * 8 + kk];
    float sv[8];
    float denom = 0.f;
    #pragma unroll
    for (int kk = 0; kk < 8; ++kk) {
      const float2* kr = reinterpret_cast<const float2*>(kb + (gbase + nb[kk]) * 80 + hh * 10);
      float acc = 0.f;
      #pragma unroll
      for (int d2 = 0; d2 < 5; ++d2) {
        float2 kv2 = kr[d2];
        acc = fmaf(qv[2 * d2], kv2.x, acc);
        acc = fmaf(qv[2 * d2 + 1], kv2.y, acc);
      }
      float s = acc * 0.31622776601683794f;  // 1/sqrt(10) as f32
      s = fminf(fmaxf(s, -5.f), 5.f);
      s = expf(s);
      sv[kk] = s;
      denom += s;
    }
    float wV[10] = {0, 0, 0, 0, 0, 0, 0, 0, 0, 0};
    #pragma unroll
    for (int kk = 0; kk < 8; ++kk) {
      const float2* vr = reinterpret_cast<const float2*>(vb + (gbase + nb[kk]) * 80 + hh * 10);
      #pragma unroll
      for (int d2 = 0; d2 < 5; ++d2) {
        float2 vv = vr[d2];
        wV[2 * d2] = fmaf(sv[kk], vv.x, wV[2 * d2]);
        wV[2 * d2 + 1] = fmaf(sv[kk], vv.y, wV[2 * d2 + 1]);
      }
    }
    float dn = denom + 1e-6f;
    #pragma unroll
    for (int d = 0; d < 10; ++d) qa[p * 80 + hh * 10 + d] = wV[d] / dn;  // overwrite own q slots (safe)
  }
  __syncthreads();
  // ---- h2 = h + attn @ Wo + bo ----
  {
    int c = tid % 80, grp = tid / 80;
    float wcol[80];
    #pragma unroll
    for (int kk = 0; kk < 80; ++kk) wcol[kk] = Wo[kk * 80 + c];
    float bias = bo[c];
    #pragma unroll
    for (int tt = 0; tt < 2; ++tt) {
      int t = grp + 4 * tt;
      if (t < 5) {
        float acc[8] = {0, 0, 0, 0, 0, 0, 0, 0};
        tile_dot20(qa + t * 640, 80, wcol, acc);
        #pragma unroll
        for (int j = 0; j < 8; ++j) {
          int rr = t * 8 + j;
          h2[rr * 80 + c] = hs[rr * 80 + c] + acc[j] + bias;
        }
      }
    }
  }
  __syncthreads();
  // ---- ts = relu(h2 @ W1 + b1) ----
  {
    int c = tid % 160, grp = tid / 160;  // 0..1
    float wcol[80];
    #pragma unroll
    for (int kk = 0; kk < 80; ++kk) wcol[kk] = W1[kk * 160 + c];
    float bias = b1[c];
    #pragma unroll
    for (int tt = 0; tt < 3; ++tt) {
      int t = grp + 2 * tt;
      if (t < 5) {
        float acc[8] = {0, 0, 0, 0, 0, 0, 0, 0};
        tile_dot20(h2 + t * 640, 80, wcol, acc);
        #pragma unroll
        for (int j = 0; j < 8; ++j) ts[(t * 8 + j) * 160 + c] = fmaxf(acc[j] + bias, 0.f);
      }
    }
  }
  __syncthreads();
  // ---- hout = h2 + ts @ W2 + b2 ----
  {
    int c = tid % 80, grp = tid / 80;
    float acc[2][8] = {{0, 0, 0, 0, 0, 0, 0, 0}, {0, 0, 0, 0, 0, 0, 0, 0}};
    #pragma unroll
    for (int half = 0; half < 2; ++half) {
      float wcol[80];
      #pragma unroll
      for (int kk = 0; kk < 80; ++kk) wcol[kk] = W2[(half * 80 + kk) * 80 + c];
      #pragma unroll
      for (int tt = 0; tt < 2; ++tt) {
        int t = grp + 4 * tt;
        if (t < 5) tile_dot20(ts + t * 1280 + half * 80, 160, wcol, acc[tt]);
      }
    }
    float bias = b2[c];
    #pragma unroll
    for (int tt = 0; tt < 2; ++tt) {
      int t = grp + 4 * tt;
      if (t < 5) {
        #pragma unroll
        for (int j = 0; j < 8; ++j) {
          int rr = t * 8 + j;
          hout[(pbase + rr) * 80 + c] = h2[rr * 80 + c] + acc[tt][j] + bias;
        }
      }
    }
  }
}

// ---------------- Readout MLP 80->40->20->64->{3,1} ----------------
__global__ __launch_bounds__(320) void readout_kernel(const float* __restrict__ h, const float* __restrict__ Wr0,
                                                      const float* __restrict__ br0, const float* __restrict__ Wr1,
                                                      const float* __restrict__ br1, const float* __restrict__ Wr2,
                                                      const float* __restrict__ br2, const float* __restrict__ Wc,
                                                      const float* __restrict__ Wb, const float* __restrict__ bb,
                                                      float* __restrict__ out) {
  __shared__ __align__(16) float hs[3200];
  __shared__ __align__(16) float y0s[40 * 40];
  __shared__ __align__(16) float y1s[40 * 20];
  __shared__ __align__(16) float y2s[40 * 64];
  size_t p0 = (size_t)blockIdx.x * 40;
  int tid = threadIdx.x;
  for (int i = tid; i < 3200; i += 320) hs[i] = h[p0 * 80 + i];
  __syncthreads();
  {  // y0 = relu(h@Wr0 + br0)   NK=80 NC=40
    int c = tid % 40, grp = tid / 40;  // 0..7
    if (grp < 5) {
      float wcol[80];
      #pragma unroll
      for (int kk = 0; kk < 80; ++kk) wcol[kk] = Wr0[kk * 40 + c];
      float bias = br0[c];
      float acc[8] = {0, 0, 0, 0, 0, 0, 0, 0};
      tile_dotk<20>(hs + grp * 640, 80, wcol, acc);
      #pragma unroll
      for (int j = 0; j < 8; ++j) y0s[(grp * 8 + j) * 40 + c] = fmaxf(acc[j] + bias, 0.f);
    }
  }
  __syncthreads();
  {  // y1 = relu(y0@Wr1 + br1)  NK=40 NC=20
    int c = tid % 20, grp = tid / 20;  // 0..15
    if (grp < 5) {
      float wcol[40];
      #pragma unroll
      for (int kk = 0; kk < 40; ++kk) wcol[kk] = Wr1[kk * 20 + c];
      float bias = br1[c];
      float acc[8] = {0, 0, 0, 0, 0, 0, 0, 0};
      tile_dotk<10>(y0s + grp * 320, 40, wcol, acc);
      #pragma unroll
      for (int j = 0; j < 8; ++j) y1s[(grp * 8 + j) * 20 + c] = fmaxf(acc[j] + bias, 0.f);
    }
  }
  __syncthreads();
  {  // y2 = y1@Wr2 + br2  NK=20 NC=64 (no relu)
    int c = tid % 64, grp = tid / 64;  // 0..4 (all active)
    float wcol[20];
    #pragma unroll
    for (int kk = 0; kk < 20; ++kk) wcol[kk] = Wr2[kk * 64 + c];
    float bias = br2[c];
    float acc[8] = {0, 0, 0, 0, 0, 0, 0, 0};
    tile_dotk<5>(y1s + grp * 160, 20, wcol, acc);
    #pragma unroll
    for (int j = 0; j < 8; ++j) y2s[(grp * 8 + j) * 64 + c] = acc[j] + bias;
  }
  __syncthreads();
  {  // out: cc = y2@Wc, beta = y2@Wb + bb
    int c = tid % 4, p = tid / 4;  // p in 0..79
    if (p < 40) {
      float wcol[64];
      if (c < 3) {
        #pragma unroll
        for (int kk = 0; kk < 64; ++kk) wcol[kk] = Wc[kk * 3 + c];
      } else {
        #pragma unroll
        for (int kk = 0; kk < 64; ++kk) wcol[kk] = Wb[kk];
      }
      float acc = 0.f;
      #pragma unroll
      for (int kk = 0; kk < 64; ++kk) acc = fmaf(y2s[p * 64 + kk], wcol[kk], acc);
      if (c == 3) acc += bb[0];
      out[(p0 + p) * 4 + c] = acc;
    }
  }
}

extern "C" void kernel_launch(void* const* d_in, const int* in_sizes, int n_in,
                              void* d_out, int out_size, void* d_ws, size_t ws_size,
                              hipStream_t stream) {
  const float* hf = (const float*)d_in[0];
  const float* gamma = (const float*)d_in[1];
  const float* beta = (const float*)d_in[2];
  const float* We = (const float*)d_in[3];
  const float* be = (const float*)d_in[4];
  const float* Wq = (const float*)d_in[5];
  const float* Wk = (const float*)d_in[6];
  const float* Wv = (const float*)d_in[7];
  const float* Wo = (const float*)d_in[8];
  const float* bo = (const float*)d_in[9];
  const float* W1 = (const float*)d_in[10];
  const float* b1 = (const float*)d_in[11];
  const float* W2 = (const float*)d_in[12];
  const float* b2 = (const float*)d_in[13];
  const float* Wr0 = (const float*)d_in[14];
  const float* br0 = (const float*)d_in[15];
  const float* Wr1 = (const float*)d_in[16];
  const float* br1 = (const float*)d_in[17];
  const float* Wr2 = (const float*)d_in[18];
  const float* br2 = (const float*)d_in[19];
  const float* Wc = (const float*)d_in[20];
  const float* Wb = (const float*)d_in[21];
  const float* bb = (const float*)d_in[22];
  float* out = (float*)d_out;

  char* wsp = (char*)d_ws;
  int* nbr = (int*)wsp;            wsp += (size_t)256000 * 8 * 4;
  float* hA = (float*)wsp;         wsp += (size_t)256000 * 80 * 4;
  float* kbuf = (float*)wsp;       wsp += (size_t)256000 * 80 * 4;
  float* vbuf = (float*)wsp;       wsp += (size_t)256000 * 80 * 4;
  float* partial = (float*)wsp;    wsp += (size_t)1000 * 18 * 4;
  float* stats = (float*)wsp;      wsp += 18 * 4;

  knn_kernel<<<1024, 256, 0, stream>>>(hf, nbr);
  bn_stat1<<<1000, 256, 0, stream>>>(hf, partial);
  bn_stat2<<<1, 256, 0, stream>>>(partial, stats);
  embed_kernel<<<6400, 320, 0, stream>>>(hf, stats, gamma, beta, We, be, hA);
  for (int l = 0; l < 10; ++l) {
    kv_kernel<<<6400, 320, 0, stream>>>(hA, Wk + (size_t)l * 6400, Wv + (size_t)l * 6400, kbuf, vbuf);
    battn_kernel<<<6400, 320, 0, stream>>>(hA, kbuf, vbuf, nbr,
                                           Wq + (size_t)l * 6400, Wo + (size_t)l * 6400, bo + (size_t)l * 80,
                                           W1 + (size_t)l * 12800, b1 + (size_t)l * 160,
                                           W2 + (size_t)l * 12800, b2 + (size_t)l * 80, hA);
  }
  readout_kernel<<<6400, 320, 0, stream>>>(hA, Wr0, br0, Wr1, br1, Wr2, br2, Wc, Wb, bb, out);
}